// Round 7
// baseline (171.400 us; speedup 1.0000x reference)
//
#include <hip/hip_runtime.h>
#include <cstdint>

typedef float  f32x16 __attribute__((ext_vector_type(16)));
typedef short  s16x8  __attribute__((ext_vector_type(8)));

__device__ __forceinline__ unsigned short f2bf(float f){
  unsigned int u = __float_as_uint(f);
  return (unsigned short)((u + 0x7FFFu + ((u >> 16) & 1u)) >> 16);   // RNE
}

// g_Wt[tap][o][ci] bf16, tap = kh*3+kw : W[o][ci][kh][kw]
__device__ alignas(16) unsigned short g_Wt[9*64*64];

__global__ void wt_kernel(const float* __restrict__ w){
  int t = blockIdx.x*256 + threadIdx.x;          // 36864 total
  if (t >= 9*64*64) return;
  int ci = t & 63, o = (t >> 6) & 63, tap = t >> 12;
  int kh = tap/3, kw = tap%3;
  g_Wt[t] = f2bf(w[((o*64 + ci)*3 + kh)*3 + kw]);
}

// double-row slab: [66 cols][2 rows][64 ci] bf16 -> 256B col-stride
// swizzle: (full byte offset within slab) ^ ((c&15)<<4)   [R4/R6-verified: 0 conflicts]
#define DSLAB 16896

// stage rows rr, rr+1 (fp32 -> bf16 transposed) into one double-row slab
__device__ __forceinline__ void stage_pair(char* slab, const float* xb,
                                           int n0, int rr, int cp, int q2){
  #pragma unroll
  for (int it = 0; it < 3; ++it){
    int q = q2 + it*8;
    if (q < 17){
      int c0 = q*4;
      int cg = n0 + c0; if (cg > 252) cg = 252;   // clamp feeds only discarded n>=254
      const float* p = xb + (size_t)(2*cp)*65536 + rr*256 + cg;
      float4 v00 = *reinterpret_cast<const float4*>(p);
      float4 v01 = *reinterpret_cast<const float4*>(p + 65536);
      float4 v10 = *reinterpret_cast<const float4*>(p + 256);
      float4 v11 = *reinterpret_cast<const float4*>(p + 65536 + 256);
      const float* a00 = (const float*)&v00; const float* a01 = (const float*)&v01;
      const float* a10 = (const float*)&v10; const float* a11 = (const float*)&v11;
      #pragma unroll
      for (int j = 0; j < 4; ++j){
        int c = c0 + j;
        if (c < 66){
          unsigned pk0 = (unsigned)f2bf(a00[j]) | ((unsigned)f2bf(a01[j]) << 16);
          unsigned pk1 = (unsigned)f2bf(a10[j]) | ((unsigned)f2bf(a11[j]) << 16);
          int swz = (c & 15) << 4;
          int base = c*256 + cp*4;
          *(unsigned*)(slab + ((base      ) ^ swz)) = pk0;
          *(unsigned*)(slab + ((base + 128) ^ swz)) = pk1;
        }
      }
    }
  }
}

__global__ __launch_bounds__(256, 4) void conv_main(const float* __restrict__ x,
                                                    const float* __restrict__ bias,
                                                    float* __restrict__ out){
  __shared__ alignas(16) char smem[2*DSLAB];     // 33792 B -> 4 blocks/CU
  const int n0 = blockIdx.x*64, y0 = blockIdx.y*8, b = blockIdx.z;
  const int rows  = min(8, 254 - y0);            // 8, last strip 6 (both even)
  const int niter = rows >> 1;
  const int tid = threadIdx.x, lane = tid & 63, wv = tid >> 6;
  const int wr = wv >> 1, wc = wv & 1;
  const int l31 = lane & 31, h = lane >> 5;
  const int cp = tid & 31, q2 = tid >> 5;        // staging task coords
  const float* xb = x + (size_t)b*64*65536;

  // ---- prologue: pairs (y0,y0+1) -> slab0, (y0+2,y0+3) -> slab1 ----
  stage_pair(smem,         xb, n0, y0,     cp, q2);
  stage_pair(smem + DSLAB, xb, n0, y0 + 2, cp, q2);
  __syncthreads();

  // ---- main loop: ring-2, slab(pair rp) = rp & 1 ----
  for (int t = 0; t < niter; ++t){
    const int y = y0 + 2*t;
    const char* s0 = smem + (t & 1)*DSLAB;        // rows y, y+1
    const char* s1 = smem + ((t + 1) & 1)*DSLAB;  // rows y+2, y+3

    f32x16 acc0, acc1;
    #pragma unroll
    for (int i = 0; i < 16; ++i){ acc0[i] = 0.f; acc1[i] = 0.f; }

    #pragma unroll
    for (int part = 0; part < 4; ++part){
      // 9 A-fragments for this k-part (36 VGPR transient, L1-hot)
      const unsigned short* wbase = &g_Wt[(wr*32 + l31)*64 + part*16 + h*8];
      s16x8 a[9];
      #pragma unroll
      for (int tap = 0; tap < 9; ++tap)
        a[tap] = *reinterpret_cast<const s16x8*>(wbase + tap*4096);

      #pragma unroll
      for (int kw = 0; kw < 3; ++kw){
        const int c = wc*32 + l31 + kw;
        const int swz = (c & 15) << 4;
        const int cb  = c*256 + (h << 4) + part*32;
        s16x8 b0 = *reinterpret_cast<const s16x8*>(s0 + ((cb      ) ^ swz)); // row y+0
        s16x8 b1 = *reinterpret_cast<const s16x8*>(s0 + ((cb + 128) ^ swz)); // row y+1
        s16x8 b2 = *reinterpret_cast<const s16x8*>(s1 + ((cb      ) ^ swz)); // row y+2
        s16x8 b3 = *reinterpret_cast<const s16x8*>(s1 + ((cb + 128) ^ swz)); // row y+3
        acc0 = __builtin_amdgcn_mfma_f32_32x32x16_bf16(a[kw    ], b0, acc0, 0, 0, 0);
        acc1 = __builtin_amdgcn_mfma_f32_32x32x16_bf16(a[kw    ], b1, acc1, 0, 0, 0);
        acc0 = __builtin_amdgcn_mfma_f32_32x32x16_bf16(a[3 + kw], b1, acc0, 0, 0, 0);
        acc1 = __builtin_amdgcn_mfma_f32_32x32x16_bf16(a[3 + kw], b2, acc1, 0, 0, 0);
        acc0 = __builtin_amdgcn_mfma_f32_32x32x16_bf16(a[6 + kw], b2, acc0, 0, 0, 0);
        acc1 = __builtin_amdgcn_mfma_f32_32x32x16_bf16(a[6 + kw], b3, acc1, 0, 0, 0);
      }
    }

    // epilogue stores (bias via L1); acc dead afterwards -> regs reusable by stage
    const int nl = n0 + wc*32 + l31;
    const int ob = wr*32 + 4*h;
    if (nl < 254){
      size_t rb = (((size_t)b*64 + ob)*254 + y)*254 + nl;
      #pragma unroll
      for (int reg = 0; reg < 16; ++reg){
        int od = (reg & 3) + 8*(reg >> 2);
        float bvr = bias[ob + od];
        out[rb + (size_t)od*64516]       = acc0[reg] + bvr;
        out[rb + (size_t)od*64516 + 254] = acc1[reg] + bvr;
      }
    }

    if (t + 1 < niter){
      // barrier 1: all LDS reads of slab (t&1) complete; stores stay in flight
      asm volatile("s_waitcnt lgkmcnt(0)\n\ts_barrier" ::: "memory");
      // stage pair rp = t+2 (rows y+4, y+5) into the freed slab
      stage_pair(smem + (t & 1)*DSLAB, xb, n0, y + 4, cp, q2);
      // barrier 2: staged data visible before next iteration reads it
      asm volatile("s_waitcnt lgkmcnt(0)\n\ts_barrier" ::: "memory");
    }
  }
}

extern "C" void kernel_launch(void* const* d_in, const int* in_sizes, int n_in,
                              void* d_out, int out_size, void* d_ws, size_t ws_size,
                              hipStream_t stream) {
  const float* x    = (const float*)d_in[0];
  const float* wgt  = (const float*)d_in[1];
  const float* bias = (const float*)d_in[2];
  float* out = (float*)d_out;

  wt_kernel<<<144, 256, 0, stream>>>(wgt);
  conv_main<<<dim3(4, 32, 8), 256, 0, stream>>>(x, bias, out);
}

// Round 8
// 129.049 us; speedup vs baseline: 1.3282x; 1.3282x over previous
//
#include <hip/hip_runtime.h>
#include <cstdint>

typedef float  f32x16 __attribute__((ext_vector_type(16)));
typedef short  s16x8  __attribute__((ext_vector_type(8)));

__device__ __forceinline__ unsigned short f2bf(float f){
  unsigned int u = __float_as_uint(f);
  return (unsigned short)((u + 0x7FFFu + ((u >> 16) & 1u)) >> 16);   // RNE
}

// g_Wt[tap][o][ci] bf16, tap = kh*3+kw : W[o][ci][kh][kw]
__device__ alignas(16) unsigned short g_Wt[9*64*64];

__global__ void wt_kernel(const float* __restrict__ w){
  int t = blockIdx.x*256 + threadIdx.x;          // 36864 total
  if (t >= 9*64*64) return;
  int ci = t & 63, o = (t >> 6) & 63, tap = t >> 12;
  int kh = tap/3, kw = tap%3;
  g_Wt[t] = f2bf(w[((o*64 + ci)*3 + kh)*3 + kw]);
}

// double-row slab: [66 cols][2 rows][64 ci] bf16 -> 256B col-stride
// swizzle: (full byte offset within slab) ^ ((c&15)<<4)   [R4/R6-verified: 0 conflicts]
#define DSLAB 16896

__global__ __launch_bounds__(256, 2) void conv_main(const float* __restrict__ x,
                                                    const float* __restrict__ bias,
                                                    float* __restrict__ out){
  __shared__ alignas(16) char smem[2*DSLAB];     // 33792 B -> 4 blocks/CU
  const int n0 = blockIdx.x*64, y0 = blockIdx.y*8, b = blockIdx.z;
  const int rows  = min(8, 254 - y0);            // 8, last strip 6 (both even)
  const int niter = rows >> 1;
  const int tid = threadIdx.x, lane = tid & 63, wv = tid >> 6;
  const int wr = wv >> 1, wc = wv & 1;
  const int l31 = lane & 31, h = lane >> 5;
  const int cp = tid & 31, q2 = tid >> 5;        // staging task coords
  const float* xb = x + (size_t)b*64*65536;

  // ---- prologue: pair (y0,y0+1) -> slab0, pair (y0+2,y0+3) -> slab1 ----
  #pragma unroll
  for (int d = 0; d < 2; ++d){
    const int rr = y0 + 2*d;
    char* slab = smem + d*DSLAB;
    #pragma unroll
    for (int it = 0; it < 3; ++it){
      int q = q2 + it*8;
      if (q < 17){
        int c0 = q*4;
        int cg = n0 + c0; if (cg > 252) cg = 252;   // clamp feeds only discarded n>=254
        const float* p = xb + (size_t)(2*cp)*65536 + rr*256 + cg;
        float4 v00 = *reinterpret_cast<const float4*>(p);
        float4 v01 = *reinterpret_cast<const float4*>(p + 65536);
        float4 v10 = *reinterpret_cast<const float4*>(p + 256);
        float4 v11 = *reinterpret_cast<const float4*>(p + 65536 + 256);
        const float* a00 = (const float*)&v00; const float* a01 = (const float*)&v01;
        const float* a10 = (const float*)&v10; const float* a11 = (const float*)&v11;
        #pragma unroll
        for (int j = 0; j < 4; ++j){
          int c = c0 + j;
          if (c < 66){
            unsigned pk0 = (unsigned)f2bf(a00[j]) | ((unsigned)f2bf(a01[j]) << 16);
            unsigned pk1 = (unsigned)f2bf(a10[j]) | ((unsigned)f2bf(a11[j]) << 16);
            int swz = (c & 15) << 4;
            int base = c*256 + cp*4;
            *(unsigned*)(slab + ((base      ) ^ swz)) = pk0;
            *(unsigned*)(slab + ((base + 128) ^ swz)) = pk1;
          }
        }
      }
    }
  }
  __syncthreads();

  // ---- main loop: ring-2; pair t lives in slab (t&1) ----
  for (int t = 0; t < niter; ++t){
    const int y = y0 + 2*t;
    const bool hav = (t + 1 < niter);
    const char* s0 = smem + (t & 1)*DSLAB;        // rows y, y+1
    const char* s1 = smem + ((t + 1) & 1)*DSLAB;  // rows y+2, y+3

    // issue-early: rows y+4, y+5 (pair t+2 -> slab (t&1), written after barrier A)
    float4 pf[3][4];
    if (hav){
      const int rr = y + 4;                      // rr+1 <= 255 by geometry
      #pragma unroll
      for (int it = 0; it < 3; ++it){
        int q = q2 + it*8;
        if (q < 17){
          int cg = n0 + q*4; if (cg > 252) cg = 252;
          const float* p = xb + (size_t)(2*cp)*65536 + rr*256 + cg;
          pf[it][0] = *reinterpret_cast<const float4*>(p);
          pf[it][1] = *reinterpret_cast<const float4*>(p + 65536);
          pf[it][2] = *reinterpret_cast<const float4*>(p + 256);
          pf[it][3] = *reinterpret_cast<const float4*>(p + 65536 + 256);
        }
      }
    }

    // compute output rows y, y+1; B-frags dedup'd across kh/row
    f32x16 acc0, acc1;
    #pragma unroll
    for (int i = 0; i < 16; ++i){ acc0[i] = 0.f; acc1[i] = 0.f; }

    #pragma unroll
    for (int kw = 0; kw < 3; ++kw){
      const int c = wc*32 + l31 + kw;
      const int swz = (c & 15) << 4;
      const int cb  = c*256 + (h << 4);
      #pragma unroll
      for (int part = 0; part < 4; ++part){
        const unsigned short* wp = &g_Wt[(kw*64 + wr*32 + l31)*64 + part*16 + h*8];
        s16x8 a0 = *reinterpret_cast<const s16x8*>(wp);            // kh=0
        s16x8 a1 = *reinterpret_cast<const s16x8*>(wp + 12288);    // kh=1
        s16x8 a2 = *reinterpret_cast<const s16x8*>(wp + 24576);    // kh=2
        const int off = cb + part*32;
        s16x8 b0 = *reinterpret_cast<const s16x8*>(s0 + ((off      ) ^ swz)); // row y+0
        s16x8 b1 = *reinterpret_cast<const s16x8*>(s0 + ((off + 128) ^ swz)); // row y+1
        s16x8 b2 = *reinterpret_cast<const s16x8*>(s1 + ((off      ) ^ swz)); // row y+2
        s16x8 b3 = *reinterpret_cast<const s16x8*>(s1 + ((off + 128) ^ swz)); // row y+3
        acc0 = __builtin_amdgcn_mfma_f32_32x32x16_bf16(a0, b0, acc0, 0, 0, 0);
        acc1 = __builtin_amdgcn_mfma_f32_32x32x16_bf16(a0, b1, acc1, 0, 0, 0);
        acc0 = __builtin_amdgcn_mfma_f32_32x32x16_bf16(a1, b1, acc0, 0, 0, 0);
        acc1 = __builtin_amdgcn_mfma_f32_32x32x16_bf16(a1, b2, acc1, 0, 0, 0);
        acc0 = __builtin_amdgcn_mfma_f32_32x32x16_bf16(a2, b2, acc0, 0, 0, 0);
        acc1 = __builtin_amdgcn_mfma_f32_32x32x16_bf16(a2, b3, acc1, 0, 0, 0);
      }
    }

    // epilogue stores (bias via L1); global stores stay in flight across barriers
    const int nl = n0 + wc*32 + l31;
    const int ob = wr*32 + 4*h;
    if (nl < 254){
      size_t rb = (((size_t)b*64 + ob)*254 + y)*254 + nl;
      #pragma unroll
      for (int reg = 0; reg < 16; ++reg){
        int od = (reg & 3) + 8*(reg >> 2);
        float bvr = bias[ob + od];
        out[rb + (size_t)od*64516]       = acc0[reg] + bvr;
        out[rb + (size_t)od*64516 + 254] = acc1[reg] + bvr;
      }
    }

    if (hav){
      // barrier A: all waves' LDS reads of slab (t&1) complete (lgkmcnt only)
      asm volatile("s_waitcnt lgkmcnt(0)\n\ts_barrier" ::: "memory");

      // write-late: cvt + ds_write pair t+2 into slab (t&1)
      char* st = smem + (t & 1)*DSLAB;
      #pragma unroll
      for (int it = 0; it < 3; ++it){
        int q = q2 + it*8;
        if (q < 17){
          int c0 = q*4;
          const float* a00 = (const float*)&pf[it][0];
          const float* a01 = (const float*)&pf[it][1];
          const float* a10 = (const float*)&pf[it][2];
          const float* a11 = (const float*)&pf[it][3];
          #pragma unroll
          for (int j = 0; j < 4; ++j){
            int cc = c0 + j;
            if (cc < 66){
              unsigned pk0 = (unsigned)f2bf(a00[j]) | ((unsigned)f2bf(a01[j]) << 16);
              unsigned pk1 = (unsigned)f2bf(a10[j]) | ((unsigned)f2bf(a11[j]) << 16);
              int swz2 = (cc & 15) << 4;
              int base = cc*256 + cp*4;
              *(unsigned*)(st + ((base      ) ^ swz2)) = pk0;
              *(unsigned*)(st + ((base + 128) ^ swz2)) = pk1;
            }
          }
        }
      }

      // barrier B: staged pair visible before next iteration reads it
      asm volatile("s_waitcnt lgkmcnt(0)\n\ts_barrier" ::: "memory");
    }
  }
}

extern "C" void kernel_launch(void* const* d_in, const int* in_sizes, int n_in,
                              void* d_out, int out_size, void* d_ws, size_t ws_size,
                              hipStream_t stream) {
  const float* x    = (const float*)d_in[0];
  const float* wgt  = (const float*)d_in[1];
  const float* bias = (const float*)d_in[2];
  float* out = (float*)d_out;

  wt_kernel<<<144, 256, 0, stream>>>(wgt);
  conv_main<<<dim3(4, 32, 8), 256, 0, stream>>>(x, bias, out);
}

// Round 9
// 128.976 us; speedup vs baseline: 1.3289x; 1.0006x over previous
//
#include <hip/hip_runtime.h>
#include <cstdint>

typedef float  f32x16 __attribute__((ext_vector_type(16)));
typedef short  s16x8  __attribute__((ext_vector_type(8)));

__device__ __forceinline__ unsigned short f2bf(float f){
  unsigned int u = __float_as_uint(f);
  return (unsigned short)((u + 0x7FFFu + ((u >> 16) & 1u)) >> 16);   // RNE
}

// g_Wt[tap][o][ci] bf16, tap = kh*3+kw : W[o][ci][kh][kw]
__device__ alignas(16) unsigned short g_Wt[9*64*64];

__global__ void wt_kernel(const float* __restrict__ w){
  int t = blockIdx.x*256 + threadIdx.x;          // 36864 total
  if (t >= 9*64*64) return;
  int ci = t & 63, o = (t >> 6) & 63, tap = t >> 12;
  int kh = tap/3, kw = tap%3;
  g_Wt[t] = f2bf(w[((o*64 + ci)*3 + kh)*3 + kw]);
}

// double-row slab: [66 cols][2 rows][64 ci] bf16 -> 256B col-stride
// swizzle: (full byte offset within slab) ^ ((c&15)<<4)   [R4/R6/R8-verified: 0 conflicts]
#define DSLAB 16896

__global__ __launch_bounds__(256, 2) void conv_main(const float* __restrict__ x,
                                                    const float* __restrict__ bias,
                                                    float* __restrict__ out){
  __shared__ alignas(16) char smem[2*DSLAB];     // 33792 B -> 4 blocks/CU resident
  // flat grid 4064 = 8 XCDs x 508; bijective XCD swizzle: XCD k owns batch k,
  // scanning (by,bx) sequentially -> 2-row halo between adjacent pairs is L2-hot.
  const int id   = blockIdx.x;
  const int wgid = (id & 7)*508 + (id >> 3);
  const int b    = wgid / 508;
  const int rem  = wgid - b*508;
  const int by   = rem >> 2, bx = rem & 3;
  const int n0 = bx*64, y0 = by*2;               // output rows y0, y0+1

  const int tid = threadIdx.x, lane = tid & 63, wv = tid >> 6;
  const int wr = wv >> 1, wc = wv & 1;
  const int l31 = lane & 31, h = lane >> 5;
  const int cp = tid & 31, q2 = tid >> 5;        // staging task coords
  const float* xb = x + (size_t)b*64*65536;

  // ---- stage once: input rows y0..y0+3 into slabs 0,1 (no loop, no ring) ----
  #pragma unroll
  for (int d = 0; d < 2; ++d){
    const int rr = y0 + 2*d;                     // rr+1 <= 255 (by <= 126)
    char* slab = smem + d*DSLAB;
    #pragma unroll
    for (int it = 0; it < 3; ++it){
      int q = q2 + it*8;
      if (q < 17){
        int c0 = q*4;
        int cg = n0 + c0; if (cg > 252) cg = 252;   // clamp feeds only discarded n>=254
        const float* p = xb + (size_t)(2*cp)*65536 + rr*256 + cg;
        float4 v00 = *reinterpret_cast<const float4*>(p);
        float4 v01 = *reinterpret_cast<const float4*>(p + 65536);
        float4 v10 = *reinterpret_cast<const float4*>(p + 256);
        float4 v11 = *reinterpret_cast<const float4*>(p + 65536 + 256);
        const float* a00 = (const float*)&v00; const float* a01 = (const float*)&v01;
        const float* a10 = (const float*)&v10; const float* a11 = (const float*)&v11;
        #pragma unroll
        for (int j = 0; j < 4; ++j){
          int c = c0 + j;
          if (c < 66){
            unsigned pk0 = (unsigned)f2bf(a00[j]) | ((unsigned)f2bf(a01[j]) << 16);
            unsigned pk1 = (unsigned)f2bf(a10[j]) | ((unsigned)f2bf(a11[j]) << 16);
            int swz = (c & 15) << 4;
            int base = c*256 + cp*4;
            *(unsigned*)(slab + ((base      ) ^ swz)) = pk0;   // row rr   (ci 2cp,2cp+1)
            *(unsigned*)(slab + ((base + 128) ^ swz)) = pk1;   // row rr+1
          }
        }
      }
    }
  }
  __syncthreads();

  // ---- compute output rows y0, y0+1; B-frags dedup'd across kh/row ----
  const char* s0 = smem;                         // rows y0,   y0+1
  const char* s1 = smem + DSLAB;                 // rows y0+2, y0+3
  f32x16 acc0, acc1;
  #pragma unroll
  for (int i = 0; i < 16; ++i){ acc0[i] = 0.f; acc1[i] = 0.f; }

  #pragma unroll
  for (int kw = 0; kw < 3; ++kw){
    const int c = wc*32 + l31 + kw;
    const int swz = (c & 15) << 4;
    const int cb  = c*256 + (h << 4);
    #pragma unroll
    for (int part = 0; part < 4; ++part){
      const unsigned short* wp = &g_Wt[(kw*64 + wr*32 + l31)*64 + part*16 + h*8];
      s16x8 a0 = *reinterpret_cast<const s16x8*>(wp);            // kh=0
      s16x8 a1 = *reinterpret_cast<const s16x8*>(wp + 12288);    // kh=1
      s16x8 a2 = *reinterpret_cast<const s16x8*>(wp + 24576);    // kh=2
      const int off = cb + part*32;
      s16x8 b0 = *reinterpret_cast<const s16x8*>(s0 + ((off      ) ^ swz)); // row y0+0
      s16x8 b1 = *reinterpret_cast<const s16x8*>(s0 + ((off + 128) ^ swz)); // row y0+1
      s16x8 b2 = *reinterpret_cast<const s16x8*>(s1 + ((off      ) ^ swz)); // row y0+2
      s16x8 b3 = *reinterpret_cast<const s16x8*>(s1 + ((off + 128) ^ swz)); // row y0+3
      acc0 = __builtin_amdgcn_mfma_f32_32x32x16_bf16(a0, b0, acc0, 0, 0, 0);
      acc1 = __builtin_amdgcn_mfma_f32_32x32x16_bf16(a0, b1, acc1, 0, 0, 0);
      acc0 = __builtin_amdgcn_mfma_f32_32x32x16_bf16(a1, b1, acc0, 0, 0, 0);
      acc1 = __builtin_amdgcn_mfma_f32_32x32x16_bf16(a1, b2, acc1, 0, 0, 0);
      acc0 = __builtin_amdgcn_mfma_f32_32x32x16_bf16(a2, b2, acc0, 0, 0, 0);
      acc1 = __builtin_amdgcn_mfma_f32_32x32x16_bf16(a2, b3, acc1, 0, 0, 0);
    }
  }

  // ---- store (bias via L1; C/D row map o = wr*32 + 4*h + (reg&3)+8*(reg>>2)) ----
  const int nl = n0 + wc*32 + l31;
  const int ob = wr*32 + 4*h;
  if (nl < 254){
    size_t rb = (((size_t)b*64 + ob)*254 + y0)*254 + nl;
    #pragma unroll
    for (int reg = 0; reg < 16; ++reg){
      int od = (reg & 3) + 8*(reg >> 2);
      float bvr = bias[ob + od];
      out[rb + (size_t)od*64516]       = acc0[reg] + bvr;
      out[rb + (size_t)od*64516 + 254] = acc1[reg] + bvr;
    }
  }
}

extern "C" void kernel_launch(void* const* d_in, const int* in_sizes, int n_in,
                              void* d_out, int out_size, void* d_ws, size_t ws_size,
                              hipStream_t stream) {
  const float* x    = (const float*)d_in[0];
  const float* wgt  = (const float*)d_in[1];
  const float* bias = (const float*)d_in[2];
  float* out = (float*)d_out;

  wt_kernel<<<144, 256, 0, stream>>>(wgt);
  conv_main<<<4064, 256, 0, stream>>>(x, bias, out);
}

// Round 10
// 114.949 us; speedup vs baseline: 1.4911x; 1.1220x over previous
//
#include <hip/hip_runtime.h>
#include <cstdint>

typedef float  f32x4 __attribute__((ext_vector_type(4)));
typedef short  s16x8 __attribute__((ext_vector_type(8)));

__device__ __forceinline__ unsigned short f2bf(float f){
  unsigned int u = __float_as_uint(f);
  return (unsigned short)((u + 0x7FFFu + ((u >> 16) & 1u)) >> 16);   // RNE
}

// g_Wt[tap][o][ci] bf16, tap = kh*3+kw : W[o][ci][kh][kw]
__device__ alignas(16) unsigned short g_Wt[9*64*64];

__global__ void wt_kernel(const float* __restrict__ w){
  int t = blockIdx.x*256 + threadIdx.x;          // 36864 total
  if (t >= 9*64*64) return;
  int ci = t & 63, o = (t >> 6) & 63, tap = t >> 12;
  int kh = tap/3, kw = tap%3;
  g_Wt[t] = f2bf(w[((o*64 + ci)*3 + kh)*3 + kw]);
}

// single-row slab: [130 cols][64 ci] bf16, 128B col-stride
// swizzle: (full byte offset) ^ (((c>>2)&3)<<5)
//   read b128 (lanes = 16 lc x 4 g): slot = (c&3)*8 + h*4 + g, lanes sharing
//   (c&3,g) differ in (c>>2)&3 -> XOR into slot bits1-2 => exactly 2-way (free).
//   write b32 (lanes vary cp): bank = cp ^ swz-bits -> bijective, conflict-free.
#define SLAB 16640

__global__ __launch_bounds__(256) void conv_main(const float* __restrict__ x,
                                                 const float* __restrict__ bias,
                                                 float* __restrict__ out){
  __shared__ alignas(16) char smem[3*SLAB];      // 49920 B -> 3 blocks/CU
  // flat 4064 = 8 XCDs x 508; XCD k scans (half,y) of batch k sequentially
  const int id   = blockIdx.x;
  const int wgid = (id & 7)*508 + (id >> 3);
  const int b    = wgid / 508;
  const int r    = wgid - b*508;
  const int half = r / 254;
  const int y    = r - half*254;
  const int n0   = half*128;

  const int tid = threadIdx.x, lane = tid & 63, wv = tid >> 6;
  const int lc = lane & 15, g = lane >> 4;
  const int cp = tid & 31, qb = tid >> 5;        // staging coords: ci-pair, quad-base
  const float* xb = x + (size_t)b*64*65536;

  // ---- stage rows y, y+1, y+2 into slabs 0,1,2 ----
  // per row: load phase (8 float4 in flight) then cvt+write phase
  #pragma unroll
  for (int rr = 0; rr < 3; ++rr){
    char* slab = smem + rr*SLAB;
    const float* xr = xb + (size_t)(2*cp)*65536 + (size_t)(y + rr)*256;

    float4 va[4][2];
    #pragma unroll
    for (int it = 0; it < 4; ++it){              // q = it*8+qb in 0..31 -> c 0..127
      const float* p = xr + (n0 + (it*8 + qb)*4);
      va[it][0] = *reinterpret_cast<const float4*>(p);
      va[it][1] = *reinterpret_cast<const float4*>(p + 65536);
    }
    float4 vt0, vt1;
    if (tid < 32){                               // tail: cols 128,129
      int cg = n0 + 128; if (cg > 252) cg = 252; // clamp feeds only discarded n>=254
      const float* p = xr + cg;
      vt0 = *reinterpret_cast<const float4*>(p);
      vt1 = *reinterpret_cast<const float4*>(p + 65536);
    }

    #pragma unroll
    for (int it = 0; it < 4; ++it){
      int c0 = (it*8 + qb)*4;
      const float* a0 = (const float*)&va[it][0];
      const float* a1 = (const float*)&va[it][1];
      #pragma unroll
      for (int j = 0; j < 4; ++j){
        int c = c0 + j;
        unsigned pk = (unsigned)f2bf(a0[j]) | ((unsigned)f2bf(a1[j]) << 16);
        int off = (c*128 + cp*4) ^ (((c >> 2) & 3) << 5);
        *reinterpret_cast<unsigned*>(slab + off) = pk;
      }
    }
    if (tid < 32){
      const float* a0 = (const float*)&vt0;
      const float* a1 = (const float*)&vt1;
      #pragma unroll
      for (int j = 0; j < 2; ++j){
        int c = 128 + j;
        unsigned pk = (unsigned)f2bf(a0[j]) | ((unsigned)f2bf(a1[j]) << 16);
        int off = (c*128 + cp*4) ^ (((c >> 2) & 3) << 5);
        *reinterpret_cast<unsigned*>(slab + off) = pk;
      }
    }
  }
  __syncthreads();

  // ---- compute: wave wv owns Cout [wv*16, wv*16+16), 8 n-tiles, 8 indep chains ----
  f32x4 acc[8];
  #pragma unroll
  for (int i = 0; i < 8; ++i) acc[i] = (f32x4){0.f,0.f,0.f,0.f};

  #pragma unroll
  for (int kh = 0; kh < 3; ++kh){
    const char* slab = smem + kh*SLAB;
    #pragma unroll
    for (int kw = 0; kw < 3; ++kw){
      #pragma unroll
      for (int h = 0; h < 2; ++h){
        // A: W[o = wv*16+lc][ci = h*32 + g*8 + e], tap = kh*3+kw
        s16x8 af = *reinterpret_cast<const s16x8*>(
            &g_Wt[((kh*3 + kw)*64 + wv*16 + lc)*64 + h*32 + g*8]);
        #pragma unroll
        for (int nt = 0; nt < 8; ++nt){
          int col = nt*16 + lc + kw;
          int off = (col*128 + h*64 + g*16) ^ (((col >> 2) & 3) << 5);
          s16x8 bf = *reinterpret_cast<const s16x8*>(slab + off);
          acc[nt] = __builtin_amdgcn_mfma_f32_16x16x32_bf16(af, bf, acc[nt], 0, 0, 0);
        }
      }
    }
  }

  // ---- store: D col=lane&15 -> n, row=4*g+reg -> o (verified map) ----
  const int ob = wv*16 + g*4;
  const float bv0 = bias[ob], bv1 = bias[ob+1], bv2 = bias[ob+2], bv3 = bias[ob+3];
  #pragma unroll
  for (int nt = 0; nt < 8; ++nt){
    int n = n0 + nt*16 + lc;
    if (n < 254){
      size_t rb = (((size_t)b*64 + ob)*254 + y)*254 + n;
      out[rb]            = acc[nt][0] + bv0;
      out[rb +   64516]  = acc[nt][1] + bv1;
      out[rb + 2*64516]  = acc[nt][2] + bv2;
      out[rb + 3*64516]  = acc[nt][3] + bv3;
    }
  }
}

extern "C" void kernel_launch(void* const* d_in, const int* in_sizes, int n_in,
                              void* d_out, int out_size, void* d_ws, size_t ws_size,
                              hipStream_t stream) {
  const float* x    = (const float*)d_in[0];
  const float* wgt  = (const float*)d_in[1];
  const float* bias = (const float*)d_in[2];
  float* out = (float*)d_out;

  wt_kernel<<<144, 256, 0, stream>>>(wgt);
  conv_main<<<4064, 256, 0, stream>>>(x, bias, out);
}